// Round 1
// baseline (1041.154 us; speedup 1.0000x reference)
//
#include <hip/hip_runtime.h>

typedef __bf16 bf16;
typedef __bf16 bf16x8 __attribute__((ext_vector_type(8)));
typedef float  f32x4  __attribute__((ext_vector_type(4)));

// Problem constants (from reference)
constexpr int Bn = 4, Hn = 16, Sn = 2048, Dh = 128;
constexpr int BQ = 64;   // queries per block (16 per wave, 4 waves)
constexpr int BK = 32;   // keys per inner iteration
// scale = 1/sqrt(128) folded with log2(e) so softmax runs in base-2 domain
constexpr float SCALE_LOG2E = 0.08838834764831845f * 1.4426950408889634f;

// LDS padded leading dims (pad +8 bf16 = 16B keeps vector alignment, breaks pow2 bank stride)
constexpr int KP = Dh + 8;   // K tile row (bf16)
constexpr int VP = BK + 8;   // V^T row
constexpr int PP = BK + 8;   // P row

__global__ __launch_bounds__(256, 2)
void fattn_kernel(const float* __restrict__ K, const float* __restrict__ V,
                  const float* __restrict__ Q, float* __restrict__ O) {
    __shared__ bf16 kS[BK][KP];        // 32 x 136 bf16 = 8704 B
    __shared__ bf16 vS[Dh][VP];        // 128 x 40 bf16 = 10240 B (V transposed: vS[d][k])
    __shared__ bf16 pS[4][16][PP];     // per-wave P tile:  4 x 16 x 40 = 5120 B

    const int tid  = threadIdx.x;
    const int wave = tid >> 6;
    const int lane = tid & 63;
    const int lg   = lane >> 4;   // quad group 0..3
    const int ln   = lane & 15;

    const int q_base = blockIdx.x * BQ;
    const int bh     = blockIdx.y;

    const float* Kb = K + (size_t)bh * Sn * Dh;
    const float* Vb = V + (size_t)bh * Sn * Dh;
    const float* Qb = Q + (size_t)bh * Sn * Dh;
    float*       Ob = O + (size_t)bh * Sn * Dh;

    // ---- Load Q fragments in MFMA A-layout: A[m=ln][k=lg*8+j], d = db*32 + lg*8 + j
    // Fold scale*log2e into the bf16 cast.
    bf16x8 qf[4];
    {
        const float* qp = Qb + (size_t)(q_base + wave * 16 + ln) * Dh + lg * 8;
        #pragma unroll
        for (int db = 0; db < 4; ++db) {
            const float* p = qp + db * 32;
            #pragma unroll
            for (int j = 0; j < 8; ++j)
                qf[db][j] = (bf16)(p[j] * SCALE_LOG2E);
        }
    }

    // Online-softmax state: rows r=0..3 of this lane's C-layout (q = q_base+wave*16+lg*4+r)
    float m_i[4], l_i[4];
    f32x4 oacc[8];   // O accumulator, C-layout: col d = dc*16+ln, row = lg*4+r
    #pragma unroll
    for (int r = 0; r < 4; ++r) { m_i[r] = -1e30f; l_i[r] = 0.0f; }
    #pragma unroll
    for (int dc = 0; dc < 8; ++dc) oacc[dc] = f32x4{0.f, 0.f, 0.f, 0.f};

    const int kb_end = q_base + BQ;   // causal: keys < q_base+BQ

    for (int kb = 0; kb < kb_end; kb += BK) {
        __syncthreads();   // previous iteration's kS/vS reads done before restage

        // ---- Stage K tile (32 x 128) as bf16, row-major
        for (int i = tid; i < BK * (Dh / 4); i += 256) {
            const int row = i >> 5;      // 32 float4 per row
            const int c4  = i & 31;
            const float4 v4 = *(const float4*)(Kb + (size_t)(kb + row) * Dh + c4 * 4);
            bf16* dst = &kS[row][c4 * 4];
            dst[0] = (bf16)v4.x; dst[1] = (bf16)v4.y;
            dst[2] = (bf16)v4.z; dst[3] = (bf16)v4.w;
        }
        // ---- Stage V tile transposed: vS[d][k]
        for (int i = tid; i < BK * (Dh / 4); i += 256) {
            const int row = i >> 5;
            const int c4  = i & 31;
            const float4 v4 = *(const float4*)(Vb + (size_t)(kb + row) * Dh + c4 * 4);
            vS[c4 * 4 + 0][row] = (bf16)v4.x;
            vS[c4 * 4 + 1][row] = (bf16)v4.y;
            vS[c4 * 4 + 2][row] = (bf16)v4.z;
            vS[c4 * 4 + 3][row] = (bf16)v4.w;
        }
        __syncthreads();

        // ---- S = Q K^T for two 16-wide key sub-tiles (keys kb+nt*16+ln as columns)
        f32x4 sacc[2];
        sacc[0] = f32x4{0.f, 0.f, 0.f, 0.f};
        sacc[1] = f32x4{0.f, 0.f, 0.f, 0.f};
        #pragma unroll
        for (int nt = 0; nt < 2; ++nt) {
            #pragma unroll
            for (int db = 0; db < 4; ++db) {
                // B-frag: K[key = nt*16+ln][d = db*32 + lg*8 + j] — same layout as A
                bf16x8 kf = *(const bf16x8*)&kS[nt * 16 + ln][db * 32 + lg * 8];
                sacc[nt] = __builtin_amdgcn_mfma_f32_16x16x32_bf16(qf[db], kf, sacc[nt], 0, 0, 0);
            }
        }

        // ---- Causal mask + online softmax (base-2), write P to per-wave LDS
        #pragma unroll
        for (int r = 0; r < 4; ++r) {
            const int qg = q_base + wave * 16 + lg * 4 + r;   // this score row's query
            float s0 = sacc[0][r];
            float s1 = sacc[1][r];
            if (kb + ln > qg)      s0 = -1e30f;
            if (kb + 16 + ln > qg) s1 = -1e30f;

            float bm = fmaxf(s0, s1);
            #pragma unroll
            for (int off = 1; off < 16; off <<= 1)
                bm = fmaxf(bm, __shfl_xor(bm, off, 64));
            const float mnew  = fmaxf(m_i[r], bm);
            const float alpha = exp2f(m_i[r] - mnew);
            const float p0 = exp2f(s0 - mnew);
            const float p1 = exp2f(s1 - mnew);
            float ps = p0 + p1;
            #pragma unroll
            for (int off = 1; off < 16; off <<= 1)
                ps += __shfl_xor(ps, off, 64);
            l_i[r] = l_i[r] * alpha + ps;
            m_i[r] = mnew;

            #pragma unroll
            for (int dc = 0; dc < 8; ++dc) oacc[dc][r] *= alpha;

            pS[wave][lg * 4 + r][ln]      = (bf16)p0;
            pS[wave][lg * 4 + r][ln + 16] = (bf16)p1;
        }

        // ---- O += P V : P re-read in A-layout (same-wave LDS RAW, no barrier needed)
        const bf16x8 pf = *(const bf16x8*)&pS[wave][ln][lg * 8];
        #pragma unroll
        for (int dc = 0; dc < 8; ++dc) {
            // B-frag: V[k = lg*8+j][d = dc*16+ln] = vS[dc*16+ln][lg*8+j]
            bf16x8 vf = *(const bf16x8*)&vS[dc * 16 + ln][lg * 8];
            oacc[dc] = __builtin_amdgcn_mfma_f32_16x16x32_bf16(pf, vf, oacc[dc], 0, 0, 0);
        }
    }

    // ---- Epilogue: O /= l, store (C-layout scatter: 4 rows x 16 consecutive floats)
    float inv_l[4];
    #pragma unroll
    for (int r = 0; r < 4; ++r) inv_l[r] = 1.0f / l_i[r];
    #pragma unroll
    for (int dc = 0; dc < 8; ++dc) {
        #pragma unroll
        for (int r = 0; r < 4; ++r) {
            const int q = q_base + wave * 16 + lg * 4 + r;
            Ob[(size_t)q * Dh + dc * 16 + ln] = oacc[dc][r] * inv_l[r];
        }
    }
}

extern "C" void kernel_launch(void* const* d_in, const int* in_sizes, int n_in,
                              void* d_out, int out_size, void* d_ws, size_t ws_size,
                              hipStream_t stream) {
    // setup_inputs order: key, value, query (all fp32)
    const float* K = (const float*)d_in[0];
    const float* V = (const float*)d_in[1];
    const float* Q = (const float*)d_in[2];
    float* O = (float*)d_out;

    dim3 grid(Sn / BQ, Bn * Hn);   // (32 q-tiles, 64 batch*head)
    fattn_kernel<<<grid, 256, 0, stream>>>(K, V, Q, O);
}

// Round 2
// 860.577 us; speedup vs baseline: 1.2098x; 1.2098x over previous
//
#include <hip/hip_runtime.h>

typedef __bf16 bf16;
typedef __bf16 bf16x8 __attribute__((ext_vector_type(8)));
typedef float  f32x4  __attribute__((ext_vector_type(4)));

// Problem constants
constexpr int Bn = 4, Hn = 16, Sn = 2048, Dh = 128;
constexpr int BQ = 128;  // queries per block: 4 waves x 32 q (2 m-tiles each)
constexpr int BK = 64;   // keys per iteration (4 n-subtiles of 16)
constexpr float SCALE_LOG2E = 0.08838834764831845f * 1.4426950408889634f;

constexpr int KP = Dh + 8;  // 136 bf16 = 272 B = 17*16B -> b128-aligned rows, minimal-conflict

__global__ __launch_bounds__(256, 2)
void fattn_kernel(const float* __restrict__ K, const float* __restrict__ V,
                  const float* __restrict__ Q, float* __restrict__ O) {
    // K tile: row-major [key][d], padded
    __shared__ bf16 kS[BK][KP];          // 64*136*2 = 17408 B
    // V^T tile: rows d (128), 64 bf16 = 8 chunks of 8; chunk c stored at c^(d&7)
    __shared__ bf16 vS[Dh * BK];         // 16384 B
    // P per wave: rows q_local (32), 64 bf16 swizzled same way
    __shared__ bf16 pS[4][32 * BK];      // 16384 B
    // total 50176 B

    const int tid  = threadIdx.x;
    const int wave = tid >> 6;
    const int lane = tid & 63;
    const int lg   = lane >> 4;
    const int ln   = lane & 15;

    const int q_base = blockIdx.x * BQ;
    const int bh     = blockIdx.y;
    const size_t boff = (size_t)bh * Sn * Dh;
    const float* Kb = K + boff;
    const float* Vb = V + boff;
    const float* Qb = Q + boff;
    float*       Ob = O + boff;

    // ---- Q fragments, A-layout: qf[qa][db], q = q_base + wave*32 + qa*16 + ln
    bf16x8 qf[2][4];
    #pragma unroll
    for (int qa = 0; qa < 2; ++qa) {
        const float* qp = Qb + (size_t)(q_base + wave * 32 + qa * 16 + ln) * Dh;
        #pragma unroll
        for (int db = 0; db < 4; ++db) {
            float4 x = *(const float4*)(qp + db * 32 + lg * 8);
            float4 y = *(const float4*)(qp + db * 32 + lg * 8 + 4);
            qf[qa][db][0] = (bf16)(x.x * SCALE_LOG2E);
            qf[qa][db][1] = (bf16)(x.y * SCALE_LOG2E);
            qf[qa][db][2] = (bf16)(x.z * SCALE_LOG2E);
            qf[qa][db][3] = (bf16)(x.w * SCALE_LOG2E);
            qf[qa][db][4] = (bf16)(y.x * SCALE_LOG2E);
            qf[qa][db][5] = (bf16)(y.y * SCALE_LOG2E);
            qf[qa][db][6] = (bf16)(y.z * SCALE_LOG2E);
            qf[qa][db][7] = (bf16)(y.w * SCALE_LOG2E);
        }
    }

    // ---- staging maps (loop-invariant)
    // K: it=0..3: idx = tid + it*256; row = idx>>4 (0..63), c8 = idx&15 (8-float col block)
    // V: d = tid&127, chb = tid>>7; co=0..3: chunk = co*2 + chb; loads V[kb+chunk*8+j][d]
    const int vd  = tid & 127;
    const int chb = tid >> 7;

    float4 kpfA[4], kpfB[4];
    float  vpf[4][8];

    auto prefetch = [&](int kb) {
        #pragma unroll
        for (int it = 0; it < 4; ++it) {
            const int idx = tid + it * 256;
            const int row = idx >> 4, c8 = idx & 15;
            const float* p = Kb + (size_t)(kb + row) * Dh + c8 * 8;
            kpfA[it] = *(const float4*)p;
            kpfB[it] = *(const float4*)(p + 4);
        }
        #pragma unroll
        for (int co = 0; co < 4; ++co) {
            const int ch = co * 2 + chb;
            const float* p = Vb + (size_t)(kb + ch * 8) * Dh + vd;
            #pragma unroll
            for (int j = 0; j < 8; ++j)
                vpf[co][j] = p[(size_t)j * Dh];
        }
    };

    prefetch(0);

    float m_i[2][4], l_i[2][4];
    f32x4 oacc[2][8];
    #pragma unroll
    for (int qa = 0; qa < 2; ++qa) {
        #pragma unroll
        for (int r = 0; r < 4; ++r) { m_i[qa][r] = -1e30f; l_i[qa][r] = 0.0f; }
        #pragma unroll
        for (int dc = 0; dc < 8; ++dc) oacc[qa][dc] = f32x4{0.f, 0.f, 0.f, 0.f};
    }

    const int kb_end = q_base + BQ;               // block processes keys [0, kb_end)
    const int my_end = q_base + wave * 32 + 32;   // this wave's q-tile needs keys < my_end

    for (int kb = 0; kb < kb_end; kb += BK) {
        __syncthreads();   // previous iteration's LDS reads complete

        // ---- write prefetched regs -> LDS (bf16, b128 stores)
        #pragma unroll
        for (int it = 0; it < 4; ++it) {
            const int idx = tid + it * 256;
            const int row = idx >> 4, c8 = idx & 15;
            bf16x8 w;
            w[0] = (bf16)kpfA[it].x; w[1] = (bf16)kpfA[it].y;
            w[2] = (bf16)kpfA[it].z; w[3] = (bf16)kpfA[it].w;
            w[4] = (bf16)kpfB[it].x; w[5] = (bf16)kpfB[it].y;
            w[6] = (bf16)kpfB[it].z; w[7] = (bf16)kpfB[it].w;
            *(bf16x8*)&kS[row][c8 * 8] = w;
        }
        #pragma unroll
        for (int co = 0; co < 4; ++co) {
            const int ch = co * 2 + chb;
            bf16x8 w;
            #pragma unroll
            for (int j = 0; j < 8; ++j) w[j] = (bf16)vpf[co][j];
            *(bf16x8*)&vS[vd * BK + ((ch ^ (vd & 7)) * 8)] = w;
        }
        __syncthreads();

        // ---- issue next tile's loads (latency hides under compute below)
        if (kb + BK < kb_end) prefetch(kb + BK);

        if (kb < my_end) {   // wave-uniform causal skip
            // ---- S = Q K^T : 4 n-subtiles x 4 k-steps x 2 q-tiles
            f32x4 sacc[2][4];
            #pragma unroll
            for (int qa = 0; qa < 2; ++qa)
                #pragma unroll
                for (int nt = 0; nt < 4; ++nt) sacc[qa][nt] = f32x4{0.f, 0.f, 0.f, 0.f};
            #pragma unroll
            for (int nt = 0; nt < 4; ++nt) {
                #pragma unroll
                for (int db = 0; db < 4; ++db) {
                    bf16x8 kf = *(const bf16x8*)&kS[nt * 16 + ln][db * 32 + lg * 8];
                    sacc[0][nt] = __builtin_amdgcn_mfma_f32_16x16x32_bf16(qf[0][db], kf, sacc[0][nt], 0, 0, 0);
                    sacc[1][nt] = __builtin_amdgcn_mfma_f32_16x16x32_bf16(qf[1][db], kf, sacc[1][nt], 0, 0, 0);
                }
            }

            // ---- online softmax (base-2), write P into per-wave swizzled LDS
            #pragma unroll
            for (int qa = 0; qa < 2; ++qa) {
                #pragma unroll
                for (int r = 0; r < 4; ++r) {
                    const int ql = qa * 16 + lg * 4 + r;           // q within block-wave tile
                    const int qg = q_base + wave * 32 + ql;        // global q
                    float s[4];
                    #pragma unroll
                    for (int nt = 0; nt < 4; ++nt) {
                        s[nt] = sacc[qa][nt][r];
                        if (kb + nt * 16 + ln > qg) s[nt] = -1e30f;
                    }
                    float bm = fmaxf(fmaxf(s[0], s[1]), fmaxf(s[2], s[3]));
                    #pragma unroll
                    for (int off = 1; off < 16; off <<= 1)
                        bm = fmaxf(bm, __shfl_xor(bm, off, 64));
                    const float mnew  = fmaxf(m_i[qa][r], bm);
                    const float alpha = exp2f(m_i[qa][r] - mnew);
                    float p[4], ps = 0.f;
                    #pragma unroll
                    for (int nt = 0; nt < 4; ++nt) { p[nt] = exp2f(s[nt] - mnew); ps += p[nt]; }
                    #pragma unroll
                    for (int off = 1; off < 16; off <<= 1)
                        ps += __shfl_xor(ps, off, 64);
                    l_i[qa][r] = l_i[qa][r] * alpha + ps;
                    m_i[qa][r] = mnew;
                    #pragma unroll
                    for (int dc = 0; dc < 8; ++dc) oacc[qa][dc][r] *= alpha;
                    #pragma unroll
                    for (int nt = 0; nt < 4; ++nt) {
                        const int ch = nt * 2 + (ln >> 3);
                        pS[wave][ql * BK + ((ch ^ (ql & 7)) * 8) + (ln & 7)] = (bf16)p[nt];
                    }
                }
            }

            // ---- O += P V  (K=64 contraction: kk=0,1)
            #pragma unroll
            for (int kk = 0; kk < 2; ++kk) {
                bf16x8 pf0 = *(const bf16x8*)&pS[wave][(0 + ln) * BK + (((kk * 4 + lg) ^ (ln & 7)) * 8)];
                bf16x8 pf1 = *(const bf16x8*)&pS[wave][(16 + ln) * BK + (((kk * 4 + lg) ^ (ln & 7)) * 8)];
                #pragma unroll
                for (int dc = 0; dc < 8; ++dc) {
                    const int d = dc * 16 + ln;
                    bf16x8 vf = *(const bf16x8*)&vS[d * BK + (((kk * 4 + lg) ^ (d & 7)) * 8)];
                    oacc[0][dc] = __builtin_amdgcn_mfma_f32_16x16x32_bf16(pf0, vf, oacc[0][dc], 0, 0, 0);
                    oacc[1][dc] = __builtin_amdgcn_mfma_f32_16x16x32_bf16(pf1, vf, oacc[1][dc], 0, 0, 0);
                }
            }
        }
    }

    // ---- epilogue
    #pragma unroll
    for (int qa = 0; qa < 2; ++qa) {
        float inv_l[4];
        #pragma unroll
        for (int r = 0; r < 4; ++r) inv_l[r] = 1.0f / l_i[qa][r];
        #pragma unroll
        for (int dc = 0; dc < 8; ++dc) {
            #pragma unroll
            for (int r = 0; r < 4; ++r) {
                const int q = q_base + wave * 32 + qa * 16 + lg * 4 + r;
                Ob[(size_t)q * Dh + dc * 16 + ln] = oacc[qa][dc][r] * inv_l[r];
            }
        }
    }
}

extern "C" void kernel_launch(void* const* d_in, const int* in_sizes, int n_in,
                              void* d_out, int out_size, void* d_ws, size_t ws_size,
                              hipStream_t stream) {
    const float* K = (const float*)d_in[0];
    const float* V = (const float*)d_in[1];
    const float* Q = (const float*)d_in[2];
    float* O = (float*)d_out;

    dim3 grid(Sn / BQ, Bn * Hn);   // (16, 64) = 1024 blocks
    fattn_kernel<<<grid, 256, 0, stream>>>(K, V, Q, O);
}

// Round 3
// 389.416 us; speedup vs baseline: 2.6736x; 2.2099x over previous
//
#include <hip/hip_runtime.h>

typedef __bf16 bf16;
typedef __bf16 bf16x8 __attribute__((ext_vector_type(8)));
typedef float  f32x4  __attribute__((ext_vector_type(4)));

// Problem constants
constexpr int Bn = 4, Hn = 16, Sn = 2048, Dh = 128;
constexpr int BQ = 128;  // queries per block: 4 waves x 32 q (2 m-tiles each)
constexpr int BK = 64;   // keys per iteration (4 n-subtiles of 16)
constexpr float SCALE_LOG2E = 0.08838834764831845f * 1.4426950408889634f;

constexpr int TILE_E = BK * Dh;            // 8192 bf16 per tile image (16 KB)
constexpr int TILES_PER_BH = Sn / BK;      // 32
constexpr size_t KV_ELEMS = (size_t)Bn * Hn * Sn * Dh;   // 16,777,216

// -------- pre-pass: fp32 K,V -> bf16 swizzled tile images in ws --------
// K image per tile: [row 0..63][chunk 0..15], chunk c of row r stored at c^(r&7)
//   (chunk = 8 bf16 = 16 B). V image per tile: transposed [d 0..127][chunk 0..7],
//   chunk c (8 keys) of row d stored at c^(d&7).
__global__ __launch_bounds__(256)
void convert_kv(const float* __restrict__ K, const float* __restrict__ V,
                bf16* __restrict__ wsK, bf16* __restrict__ wsV) {
    const int tt  = blockIdx.x;           // bh*32 + tile  (0..2047)
    const int tid = threadIdx.x;
    if (blockIdx.y == 0) {
        const float* src = K + (size_t)tt * TILE_E;
        bf16* dst = wsK + (size_t)tt * TILE_E;
        #pragma unroll
        for (int k = 0; k < 4; ++k) {
            const int idx = tid + k * 256;
            const int row = idx >> 4, ch = idx & 15;
            const float* p = src + row * 128 + ch * 8;
            const float4 a = *(const float4*)p;
            const float4 b = *(const float4*)(p + 4);
            bf16x8 w;
            w[0] = (bf16)a.x; w[1] = (bf16)a.y; w[2] = (bf16)a.z; w[3] = (bf16)a.w;
            w[4] = (bf16)b.x; w[5] = (bf16)b.y; w[6] = (bf16)b.z; w[7] = (bf16)b.w;
            *(bf16x8*)&dst[row * 128 + ((ch ^ (row & 7)) * 8)] = w;
        }
    } else {
        const float* src = V + (size_t)tt * TILE_E;
        bf16* dst = wsV + (size_t)tt * TILE_E;
        #pragma unroll
        for (int k = 0; k < 4; ++k) {
            const int idx = tid + k * 256;
            const int d = idx & 127, ch = idx >> 7;
            bf16x8 w;
            #pragma unroll
            for (int j = 0; j < 8; ++j)
                w[j] = (bf16)src[(ch * 8 + j) * 128 + d];
            *(bf16x8*)&dst[d * 64 + ((ch ^ (d & 7)) * 8)] = w;
        }
    }
}

__device__ __forceinline__ void ld16(const bf16* g, bf16* l) {
    __builtin_amdgcn_global_load_lds(
        (const __attribute__((address_space(1))) void*)g,
        (__attribute__((address_space(3))) void*)l, 16, 0, 0);
}

// -------- main flash-attention kernel (bf16 staged K/V) --------
__global__ __launch_bounds__(256, 2)
void fattn_main(const bf16* __restrict__ Kw, const bf16* __restrict__ Vw,
                const float* __restrict__ Q, float* __restrict__ O) {
    __shared__ bf16 kS[2][TILE_E];   // 2 x 16 KB; kS[cur] becomes the P buffer mid-iter
    __shared__ bf16 vS[2][TILE_E];   // 2 x 16 KB  (total 64 KB)

    const int tid  = threadIdx.x;
    const int wave = tid >> 6;
    const int lane = tid & 63;
    const int lg   = lane >> 4;
    const int ln   = lane & 15;

    const int bh     = blockIdx.x;                          // bh fastest -> XCD pinning
    const int q_tile = (int)gridDim.y - 1 - (int)blockIdx.y; // longest q-tiles first
    const int q_base = q_tile * BQ;

    const bf16*  Kt = Kw + (size_t)bh * TILES_PER_BH * TILE_E;
    const bf16*  Vt = Vw + (size_t)bh * TILES_PER_BH * TILE_E;
    const float* Qb = Q + (size_t)bh * Sn * Dh;
    float*       Ob = O + (size_t)bh * Sn * Dh;

    // async tile copy: each wave moves its 4 KB quarter, 4 x 1 KB wave-chunks
    const int goff = wave * 2048 + lane * 8;  // elems; lane*16B
    const int loff = wave * 2048;             // wave-uniform LDS base
    auto issue_tile = [&](const bf16* src, bf16* dst) {
        #pragma unroll
        for (int i = 0; i < 4; ++i)
            ld16(src + goff + i * 512, dst + loff + i * 512);
    };

    // prologue: tile 0 into buffer 0 (drained at first __syncthreads)
    issue_tile(Kt, kS[0]);
    issue_tile(Vt, vS[0]);

    // Q fragments (A-layout), scale*log2e folded into the bf16 cast
    bf16x8 qf[2][4];
    #pragma unroll
    for (int qa = 0; qa < 2; ++qa) {
        const float* qp = Qb + (size_t)(q_base + wave * 32 + qa * 16 + ln) * Dh;
        #pragma unroll
        for (int db = 0; db < 4; ++db) {
            const float4 x = *(const float4*)(qp + db * 32 + lg * 8);
            const float4 y = *(const float4*)(qp + db * 32 + lg * 8 + 4);
            qf[qa][db][0] = (bf16)(x.x * SCALE_LOG2E);
            qf[qa][db][1] = (bf16)(x.y * SCALE_LOG2E);
            qf[qa][db][2] = (bf16)(x.z * SCALE_LOG2E);
            qf[qa][db][3] = (bf16)(x.w * SCALE_LOG2E);
            qf[qa][db][4] = (bf16)(y.x * SCALE_LOG2E);
            qf[qa][db][5] = (bf16)(y.y * SCALE_LOG2E);
            qf[qa][db][6] = (bf16)(y.z * SCALE_LOG2E);
            qf[qa][db][7] = (bf16)(y.w * SCALE_LOG2E);
        }
    }

    float m_i[2][4], l_i[2][4];
    f32x4 oacc[2][8];
    #pragma unroll
    for (int qa = 0; qa < 2; ++qa) {
        #pragma unroll
        for (int r = 0; r < 4; ++r) { m_i[qa][r] = -1e30f; l_i[qa][r] = 0.0f; }
        #pragma unroll
        for (int dc = 0; dc < 8; ++dc) oacc[qa][dc] = f32x4{0.f, 0.f, 0.f, 0.f};
    }

    const int kb_end = q_base + BQ;
    const int my_end = q_base + wave * 32 + 32;

    for (int kb = 0, it = 0; kb < kb_end; kb += BK, ++it) {
        const int cur = it & 1, nxt = cur ^ 1;
        const bool more   = (kb + BK) < kb_end;
        const bool active = kb < my_end;

        __syncthreads();   // B1: buf[cur] K/V tiles resident (drains async loads)

        // ---- S = Q K^T on kS[cur]
        f32x4 sacc[2][4];
        if (active) {
            #pragma unroll
            for (int qa = 0; qa < 2; ++qa)
                #pragma unroll
                for (int nt = 0; nt < 4; ++nt) sacc[qa][nt] = f32x4{0.f, 0.f, 0.f, 0.f};
            const bf16* kc = kS[cur];
            #pragma unroll
            for (int nt = 0; nt < 4; ++nt) {
                #pragma unroll
                for (int db = 0; db < 4; ++db) {
                    const bf16x8 kf = *(const bf16x8*)&kc[(nt * 16 + ln) * 128 + (((db * 4 + lg) ^ (ln & 7)) * 8)];
                    sacc[0][nt] = __builtin_amdgcn_mfma_f32_16x16x32_bf16(qf[0][db], kf, sacc[0][nt], 0, 0, 0);
                    sacc[1][nt] = __builtin_amdgcn_mfma_f32_16x16x32_bf16(qf[1][db], kf, sacc[1][nt], 0, 0, 0);
                }
            }
        }

        __syncthreads();   // B2: all waves done reading kS[cur] -> it becomes P space

        // issue next tile AFTER B2: B2 drains nothing; loads get softmax+PV cover,
        // drained at next iteration's B1.
        if (more) {
            issue_tile(Kt + (size_t)(it + 1) * TILE_E, kS[nxt]);
            issue_tile(Vt + (size_t)(it + 1) * TILE_E, vS[nxt]);
        }

        if (active) {
            // ---- online softmax (base-2); P -> this wave's 4 KB slice of kS[cur]
            bf16* pw = kS[cur] + wave * 2048;   // P[32 q][64 k], chunk c of row q at c^(q&7)
            #pragma unroll
            for (int qa = 0; qa < 2; ++qa) {
                #pragma unroll
                for (int r = 0; r < 4; ++r) {
                    const int ql = qa * 16 + lg * 4 + r;
                    const int qg = q_base + wave * 32 + ql;
                    float s[4];
                    #pragma unroll
                    for (int nt = 0; nt < 4; ++nt) {
                        s[nt] = sacc[qa][nt][r];
                        if (kb + nt * 16 + ln > qg) s[nt] = -1e30f;
                    }
                    float bm = fmaxf(fmaxf(s[0], s[1]), fmaxf(s[2], s[3]));
                    #pragma unroll
                    for (int off = 1; off < 16; off <<= 1)
                        bm = fmaxf(bm, __shfl_xor(bm, off, 64));
                    const float mnew  = fmaxf(m_i[qa][r], bm);
                    const float alpha = exp2f(m_i[qa][r] - mnew);
                    float p[4], ps = 0.f;
                    #pragma unroll
                    for (int nt = 0; nt < 4; ++nt) { p[nt] = exp2f(s[nt] - mnew); ps += p[nt]; }
                    #pragma unroll
                    for (int off = 1; off < 16; off <<= 1)
                        ps += __shfl_xor(ps, off, 64);
                    l_i[qa][r] = l_i[qa][r] * alpha + ps;
                    m_i[qa][r] = mnew;
                    #pragma unroll
                    for (int dc = 0; dc < 8; ++dc) oacc[qa][dc][r] *= alpha;
                    #pragma unroll
                    for (int nt = 0; nt < 4; ++nt) {
                        const int ch = nt * 2 + (ln >> 3);
                        pw[ql * 64 + ((ch ^ (ql & 7)) * 8) + (ln & 7)] = (bf16)p[nt];
                    }
                }
            }

            // ---- O += P V on vS[cur] (K=64: kk=0,1)
            const bf16* vc = vS[cur];
            #pragma unroll
            for (int kk = 0; kk < 2; ++kk) {
                const bf16x8 pf0 = *(const bf16x8*)&pw[(0  + ln) * 64 + (((kk * 4 + lg) ^ (ln & 7)) * 8)];
                const bf16x8 pf1 = *(const bf16x8*)&pw[(16 + ln) * 64 + (((kk * 4 + lg) ^ (ln & 7)) * 8)];
                #pragma unroll
                for (int dc = 0; dc < 8; ++dc) {
                    const bf16x8 vf = *(const bf16x8*)&vc[(dc * 16 + ln) * 64 + (((kk * 4 + lg) ^ (ln & 7)) * 8)];
                    oacc[0][dc] = __builtin_amdgcn_mfma_f32_16x16x32_bf16(pf0, vf, oacc[0][dc], 0, 0, 0);
                    oacc[1][dc] = __builtin_amdgcn_mfma_f32_16x16x32_bf16(pf1, vf, oacc[1][dc], 0, 0, 0);
                }
            }
        }
    }

    // ---- epilogue
    #pragma unroll
    for (int qa = 0; qa < 2; ++qa) {
        float inv_l[4];
        #pragma unroll
        for (int r = 0; r < 4; ++r) inv_l[r] = 1.0f / l_i[qa][r];
        #pragma unroll
        for (int dc = 0; dc < 8; ++dc) {
            #pragma unroll
            for (int r = 0; r < 4; ++r) {
                const int q = q_base + wave * 32 + qa * 16 + lg * 4 + r;
                Ob[(size_t)q * Dh + dc * 16 + ln] = oacc[qa][dc][r] * inv_l[r];
            }
        }
    }
}

// -------- fallback (round-2 kernel) if ws is too small for bf16 K/V --------
__global__ __launch_bounds__(256, 2)
void fattn_fallback(const float* __restrict__ K, const float* __restrict__ V,
                    const float* __restrict__ Q, float* __restrict__ O) {
    constexpr int KP = Dh + 8;
    __shared__ bf16 kS[BK][KP];
    __shared__ bf16 vS[Dh * BK];
    __shared__ bf16 pS[4][32 * BK];

    const int tid  = threadIdx.x;
    const int wave = tid >> 6;
    const int lane = tid & 63;
    const int lg   = lane >> 4;
    const int ln   = lane & 15;

    const int q_base = blockIdx.x * BQ;
    const int bh     = blockIdx.y;
    const size_t boff = (size_t)bh * Sn * Dh;
    const float* Kb = K + boff;
    const float* Vb = V + boff;
    const float* Qb = Q + boff;
    float*       Ob = O + boff;

    bf16x8 qf[2][4];
    #pragma unroll
    for (int qa = 0; qa < 2; ++qa) {
        const float* qp = Qb + (size_t)(q_base + wave * 32 + qa * 16 + ln) * Dh;
        #pragma unroll
        for (int db = 0; db < 4; ++db) {
            float4 x = *(const float4*)(qp + db * 32 + lg * 8);
            float4 y = *(const float4*)(qp + db * 32 + lg * 8 + 4);
            qf[qa][db][0] = (bf16)(x.x * SCALE_LOG2E); qf[qa][db][1] = (bf16)(x.y * SCALE_LOG2E);
            qf[qa][db][2] = (bf16)(x.z * SCALE_LOG2E); qf[qa][db][3] = (bf16)(x.w * SCALE_LOG2E);
            qf[qa][db][4] = (bf16)(y.x * SCALE_LOG2E); qf[qa][db][5] = (bf16)(y.y * SCALE_LOG2E);
            qf[qa][db][6] = (bf16)(y.z * SCALE_LOG2E); qf[qa][db][7] = (bf16)(y.w * SCALE_LOG2E);
        }
    }

    const int vd  = tid & 127;
    const int chb = tid >> 7;
    float4 kpfA[4], kpfB[4];
    float  vpf[4][8];
    auto prefetch = [&](int kb) {
        #pragma unroll
        for (int it = 0; it < 4; ++it) {
            const int idx = tid + it * 256;
            const int row = idx >> 4, c8 = idx & 15;
            const float* p = Kb + (size_t)(kb + row) * Dh + c8 * 8;
            kpfA[it] = *(const float4*)p;
            kpfB[it] = *(const float4*)(p + 4);
        }
        #pragma unroll
        for (int co = 0; co < 4; ++co) {
            const int ch = co * 2 + chb;
            const float* p = Vb + (size_t)(kb + ch * 8) * Dh + vd;
            #pragma unroll
            for (int j = 0; j < 8; ++j) vpf[co][j] = p[(size_t)j * Dh];
        }
    };
    prefetch(0);

    float m_i[2][4], l_i[2][4];
    f32x4 oacc[2][8];
    #pragma unroll
    for (int qa = 0; qa < 2; ++qa) {
        #pragma unroll
        for (int r = 0; r < 4; ++r) { m_i[qa][r] = -1e30f; l_i[qa][r] = 0.0f; }
        #pragma unroll
        for (int dc = 0; dc < 8; ++dc) oacc[qa][dc] = f32x4{0.f, 0.f, 0.f, 0.f};
    }

    const int kb_end = q_base + BQ;
    const int my_end = q_base + wave * 32 + 32;

    for (int kb = 0; kb < kb_end; kb += BK) {
        __syncthreads();
        #pragma unroll
        for (int it = 0; it < 4; ++it) {
            const int idx = tid + it * 256;
            const int row = idx >> 4, c8 = idx & 15;
            bf16x8 w;
            w[0] = (bf16)kpfA[it].x; w[1] = (bf16)kpfA[it].y;
            w[2] = (bf16)kpfA[it].z; w[3] = (bf16)kpfA[it].w;
            w[4] = (bf16)kpfB[it].x; w[5] = (bf16)kpfB[it].y;
            w[6] = (bf16)kpfB[it].z; w[7] = (bf16)kpfB[it].w;
            *(bf16x8*)&kS[row][c8 * 8] = w;
        }
        #pragma unroll
        for (int co = 0; co < 4; ++co) {
            const int ch = co * 2 + chb;
            bf16x8 w;
            #pragma unroll
            for (int j = 0; j < 8; ++j) w[j] = (bf16)vpf[co][j];
            *(bf16x8*)&vS[vd * BK + ((ch ^ (vd & 7)) * 8)] = w;
        }
        __syncthreads();
        if (kb + BK < kb_end) prefetch(kb + BK);

        if (kb < my_end) {
            f32x4 sacc[2][4];
            #pragma unroll
            for (int qa = 0; qa < 2; ++qa)
                #pragma unroll
                for (int nt = 0; nt < 4; ++nt) sacc[qa][nt] = f32x4{0.f, 0.f, 0.f, 0.f};
            #pragma unroll
            for (int nt = 0; nt < 4; ++nt) {
                #pragma unroll
                for (int db = 0; db < 4; ++db) {
                    bf16x8 kf = *(const bf16x8*)&kS[nt * 16 + ln][db * 32 + lg * 8];
                    sacc[0][nt] = __builtin_amdgcn_mfma_f32_16x16x32_bf16(qf[0][db], kf, sacc[0][nt], 0, 0, 0);
                    sacc[1][nt] = __builtin_amdgcn_mfma_f32_16x16x32_bf16(qf[1][db], kf, sacc[1][nt], 0, 0, 0);
                }
            }
            #pragma unroll
            for (int qa = 0; qa < 2; ++qa) {
                #pragma unroll
                for (int r = 0; r < 4; ++r) {
                    const int ql = qa * 16 + lg * 4 + r;
                    const int qg = q_base + wave * 32 + ql;
                    float s[4];
                    #pragma unroll
                    for (int nt = 0; nt < 4; ++nt) {
                        s[nt] = sacc[qa][nt][r];
                        if (kb + nt * 16 + ln > qg) s[nt] = -1e30f;
                    }
                    float bm = fmaxf(fmaxf(s[0], s[1]), fmaxf(s[2], s[3]));
                    #pragma unroll
                    for (int off = 1; off < 16; off <<= 1)
                        bm = fmaxf(bm, __shfl_xor(bm, off, 64));
                    const float mnew  = fmaxf(m_i[qa][r], bm);
                    const float alpha = exp2f(m_i[qa][r] - mnew);
                    float p[4], ps = 0.f;
                    #pragma unroll
                    for (int nt = 0; nt < 4; ++nt) { p[nt] = exp2f(s[nt] - mnew); ps += p[nt]; }
                    #pragma unroll
                    for (int off = 1; off < 16; off <<= 1)
                        ps += __shfl_xor(ps, off, 64);
                    l_i[qa][r] = l_i[qa][r] * alpha + ps;
                    m_i[qa][r] = mnew;
                    #pragma unroll
                    for (int dc = 0; dc < 8; ++dc) oacc[qa][dc][r] *= alpha;
                    #pragma unroll
                    for (int nt = 0; nt < 4; ++nt) {
                        const int ch = nt * 2 + (ln >> 3);
                        pS[wave][ql * BK + ((ch ^ (ql & 7)) * 8) + (ln & 7)] = (bf16)p[nt];
                    }
                }
            }
            #pragma unroll
            for (int kk = 0; kk < 2; ++kk) {
                bf16x8 pf0 = *(const bf16x8*)&pS[wave][(0 + ln) * BK + (((kk * 4 + lg) ^ (ln & 7)) * 8)];
                bf16x8 pf1 = *(const bf16x8*)&pS[wave][(16 + ln) * BK + (((kk * 4 + lg) ^ (ln & 7)) * 8)];
                #pragma unroll
                for (int dc = 0; dc < 8; ++dc) {
                    const int d = dc * 16 + ln;
                    bf16x8 vf = *(const bf16x8*)&vS[d * BK + (((kk * 4 + lg) ^ (d & 7)) * 8)];
                    oacc[0][dc] = __builtin_amdgcn_mfma_f32_16x16x32_bf16(pf0, vf, oacc[0][dc], 0, 0, 0);
                    oacc[1][dc] = __builtin_amdgcn_mfma_f32_16x16x32_bf16(pf1, vf, oacc[1][dc], 0, 0, 0);
                }
            }
        }
    }

    #pragma unroll
    for (int qa = 0; qa < 2; ++qa) {
        float inv_l[4];
        #pragma unroll
        for (int r = 0; r < 4; ++r) inv_l[r] = 1.0f / l_i[qa][r];
        #pragma unroll
        for (int dc = 0; dc < 8; ++dc) {
            #pragma unroll
            for (int r = 0; r < 4; ++r) {
                const int q = q_base + wave * 32 + qa * 16 + lg * 4 + r;
                Ob[(size_t)q * Dh + dc * 16 + ln] = oacc[qa][dc][r] * inv_l[r];
            }
        }
    }
}

extern "C" void kernel_launch(void* const* d_in, const int* in_sizes, int n_in,
                              void* d_out, int out_size, void* d_ws, size_t ws_size,
                              hipStream_t stream) {
    const float* K = (const float*)d_in[0];
    const float* V = (const float*)d_in[1];
    const float* Q = (const float*)d_in[2];
    float* O = (float*)d_out;

    const size_t ws_needed = 2 * KV_ELEMS * sizeof(bf16);   // 64 MB
    if (ws_size >= ws_needed) {
        bf16* wsK = (bf16*)d_ws;
        bf16* wsV = wsK + KV_ELEMS;
        convert_kv<<<dim3(Bn * Hn * TILES_PER_BH, 2), 256, 0, stream>>>(K, V, wsK, wsV);
        fattn_main<<<dim3(Bn * Hn, Sn / BQ), 256, 0, stream>>>(wsK, wsV, Q, O);
    } else {
        fattn_fallback<<<dim3(Sn / BQ, Bn * Hn), 256, 0, stream>>>(K, V, Q, O);
    }
}